// Round 21
// baseline (227.361 us; speedup 1.0000x reference)
//
#include <hip/hip_runtime.h>
#include <cstdint>
#include <math.h>

typedef unsigned short u16;
typedef __bf16 bf16x8 __attribute__((ext_vector_type(8)));
typedef float f32x4 __attribute__((ext_vector_type(4)));

constexpr int Bc = 2, Sc = 2048, Dc = 1024, Hc = 16, DHc = 64;

__device__ __forceinline__ u16 f2bf(float f) {
  uint32_t u = __builtin_bit_cast(uint32_t, f);
  u += 0x7fffu + ((u >> 16) & 1u);
  return (u16)(u >> 16);
}
__device__ __forceinline__ float bf2f(u16 h) {
  uint32_t u = ((uint32_t)h) << 16;
  return __builtin_bit_cast(float, u);
}
__device__ __forceinline__ f32x4 mfma16(bf16x8 a, bf16x8 b, f32x4 c) {
  return __builtin_amdgcn_mfma_f32_16x16x32_bf16(a, b, c, 0, 0, 0);
}
// async global->LDS, 16B per lane; LDS base must be wave-uniform, global addr per-lane
__device__ __forceinline__ void gload16(const void* g, void* l) {
  __builtin_amdgcn_global_load_lds((const uint32_t*)g, (uint32_t*)l, 16, 0, 0);
}
// two f32x4 -> bf16x8 (RNE)
__device__ __forceinline__ bf16x8 pk8(f32x4 a, f32x4 b) {
  alignas(16) u16 t[8];
  #pragma unroll
  for (int j = 0; j < 4; ++j) { t[j] = f2bf(a[j]); t[4 + j] = f2bf(b[j]); }
  return *reinterpret_cast<const bf16x8*>(t);
}

// ---------------- single-launch f32 -> bf16 conversion of all 7 tensors ----------------
__global__ __launch_bounds__(256) void cvt_all(
    const float* __restrict__ q, const float* __restrict__ k, const float* __restrict__ v,
    const float* __restrict__ Wq, const float* __restrict__ Wk,
    const float* __restrict__ Wv, const float* __restrict__ Wo,
    u16* __restrict__ qo, u16* __restrict__ ko, u16* __restrict__ vo,
    u16* __restrict__ Wqo, u16* __restrict__ Wko, u16* __restrict__ Wvo,
    u16* __restrict__ Woo) {
  constexpr int NQ = Bc * Sc * Dc / 4;      // 1048576 float4 per q/k/v
  constexpr int NW = Hc * DHc * Dc / 4;     // 262144 per Wq/Wk
  constexpr int NS = DHc * Dc / 4;          // 16384 per Wv/Wo
  constexpr int C1 = NQ, C2 = 2 * NQ, C3 = 3 * NQ;
  constexpr int C4 = C3 + NW, C5 = C4 + NW, C6 = C5 + NS, C7 = C6 + NS;
  const int i = blockIdx.x * 256 + threadIdx.x;
  if (i >= C7) return;
  const float* src; u16* dst; int j;
  if (i < C1)      { src = q;  dst = qo;  j = i; }
  else if (i < C2) { src = k;  dst = ko;  j = i - C1; }
  else if (i < C3) { src = v;  dst = vo;  j = i - C2; }
  else if (i < C4) { src = Wq; dst = Wqo; j = i - C3; }
  else if (i < C5) { src = Wk; dst = Wko; j = i - C4; }
  else if (i < C6) { src = Wv; dst = Wvo; j = i - C5; }
  else             { src = Wo; dst = Woo; j = i - C6; }
  float4 x = reinterpret_cast<const float4*>(src)[j];
  ushort4 o;
  o.x = f2bf(x.x); o.y = f2bf(x.y); o.z = f2bf(x.z); o.w = f2bf(x.w);
  reinterpret_cast<ushort4*>(dst)[j] = o;
}

// ---------------- combined q+k+v projection GEMM, 128x64 tiles for occupancy.
// Grid (32, 16, 3): x = m-tile (XCD-grouped A panel), y = n-tile (64 wide),
// z selects {q, k, v}; z==2 active only at y==0 (N=64). ~4 blocks/CU,
// ~24 waves/CU vs 2.1 blocks at the old 128x128 tile -> barrier stalls covered.
__global__ __launch_bounds__(256) void gemm_qkv(
    const u16* __restrict__ qbf, const u16* __restrict__ kbf, const u16* __restrict__ vbf,
    const u16* __restrict__ Wqb, const u16* __restrict__ Wkb, const u16* __restrict__ Wvb,
    const float* __restrict__ bq, const float* __restrict__ bk, const float* __restrict__ bv,
    float qscale, u16* __restrict__ qh, u16* __restrict__ kh, u16* __restrict__ vT) {
  constexpr int K = 1024;
  const int z = blockIdx.z;
  if (z == 2 && blockIdx.y != 0) return;
  const u16* A  = z == 0 ? qbf : (z == 1 ? kbf : vbf);
  const u16* Bw = z == 0 ? Wqb : (z == 1 ? Wkb : Wvb);
  const float* bias = z == 0 ? bq : (z == 1 ? bk : bv);
  const float scale = z == 0 ? qscale : 1.0f;

  __shared__ u16 As[128 * 32];
  __shared__ u16 Bs[64 * 32];
  const int tid = threadIdx.x;
  const int lane = tid & 63;
  const int w = tid >> 6, wm = w >> 1, wn = w & 1;
  const int lo = lane & 15, hi = lane >> 4;
  const int m0 = blockIdx.x * 128, n0 = blockIdx.y * 64;
  const int r16 = lane >> 2;
  const int c8 = (lane & 3) * 8;
  const f32x4 vzero = {0.f, 0.f, 0.f, 0.f};

  f32x4 acc[4][2];
  #pragma unroll
  for (int i = 0; i < 4; ++i)
    #pragma unroll
    for (int j = 0; j < 2; ++j) acc[i][j] = vzero;

  for (int k0 = 0; k0 < K; k0 += 32) {
    #pragma unroll
    for (int it = 0; it < 2; ++it) {
      const int rg = w * 2 + it;      // A: 8 x 16-row groups
      gload16(&A[(long)(m0 + rg * 16 + r16) * K + k0 + c8], &As[rg * 512]);
    }
    gload16(&Bw[(long)(n0 + w * 16 + r16) * K + k0 + c8], &Bs[w * 512]);
    __syncthreads();
    bf16x8 af[4], bfr[2];
    #pragma unroll
    for (int mi = 0; mi < 4; ++mi)
      af[mi] = *reinterpret_cast<const bf16x8*>(&As[(wm * 64 + mi * 16 + lo) * 32 + hi * 8]);
    #pragma unroll
    for (int nj = 0; nj < 2; ++nj)
      bfr[nj] = *reinterpret_cast<const bf16x8*>(&Bs[(wn * 32 + nj * 16 + lo) * 32 + hi * 8]);
    #pragma unroll
    for (int mi = 0; mi < 4; ++mi)
      #pragma unroll
      for (int nj = 0; nj < 2; ++nj)
        acc[mi][nj] = mfma16(af[mi], bfr[nj], acc[mi][nj]);
    __syncthreads();
  }

  #pragma unroll
  for (int nj = 0; nj < 2; ++nj) {
    const int n = n0 + wn * 32 + nj * 16 + lo;
    const float bb = bias[n];
    #pragma unroll
    for (int mi = 0; mi < 4; ++mi) {
      #pragma unroll
      for (int r = 0; r < 4; ++r) {
        const int mm = m0 + wm * 64 + mi * 16 + hi * 4 + r;
        const int bidx = mm >> 11, ss = mm & 2047;
        const float val = (acc[mi][nj][r] + bb) * scale;
        if (z < 2) {
          const int hh = n >> 6, ee = n & 63;
          const long idx = bidx * 2097152L + ss * 64L + hh * 131072L + ee;
          (z ? kh : qh)[idx] = f2bf(val);
        } else {
          vT[bidx * 131072L + n * 2048L + ss] = f2bf(val);
        }
      }
    }
  }
}

// ---------------- fused mean-over-heads + final projection GEMM
// out[b,s,n] = sum_e (mean_h outh[b,h,s,e]) * Wo[n][e]
// Grid (32, 8): x = m-tile (XCD-grouped A re-stage), y = n-tile. K=64 whole.
__global__ __launch_bounds__(256) void gemm_final(
    const u16* __restrict__ outh, const u16* __restrict__ Wob,
    float* __restrict__ out) {
  constexpr int LDP = 72;  // 64 + 8 pad -> <=2-way ds_read_b128 conflicts
  __shared__ u16 As[128 * LDP];
  __shared__ u16 Bs[128 * LDP];
  const int tid = threadIdx.x;
  const int lane = tid & 63;
  const int w = tid >> 6, wm = w >> 1, wn = w & 1;
  const int lo = lane & 15, hi = lane >> 4;
  const int m0 = blockIdx.x * 128, n0 = blockIdx.y * 128;
  const f32x4 vzero = {0.f, 0.f, 0.f, 0.f};

  // stage A = mean over 16 heads (reg-accumulate, coalesced 128B rows)
  {
    const int row = tid >> 1;         // 0..127
    const int c0 = (tid & 1) * 32;    // 0 / 32
    const int mm = m0 + row;
    const int b = mm >> 11, ss = mm & 2047;
    float acc[32];
    #pragma unroll
    for (int j = 0; j < 32; ++j) acc[j] = 0.f;
    for (int h = 0; h < Hc; ++h) {
      const u16* p = &outh[((long)(b * Hc + h) * Sc + ss) * DHc + c0];
      #pragma unroll
      for (int g = 0; g < 4; ++g) {
        alignas(16) u16 t[8];
        *reinterpret_cast<uint4*>(t) = *reinterpret_cast<const uint4*>(&p[g * 8]);
        #pragma unroll
        for (int j = 0; j < 8; ++j) acc[g * 8 + j] += bf2f(t[j]);
      }
    }
    #pragma unroll
    for (int g = 0; g < 4; ++g) {
      alignas(16) u16 t[8];
      #pragma unroll
      for (int j = 0; j < 8; ++j) t[j] = f2bf(acc[g * 8 + j] * 0.0625f);
      *reinterpret_cast<uint4*>(&As[row * LDP + c0 + g * 8]) =
          *reinterpret_cast<const uint4*>(t);
    }
    // stage B = Wo rows n0..n0+127
    const u16* pb = &Wob[(long)(n0 + row) * DHc + c0];
    #pragma unroll
    for (int g = 0; g < 4; ++g)
      *reinterpret_cast<uint4*>(&Bs[row * LDP + c0 + g * 8]) =
          *reinterpret_cast<const uint4*>(&pb[g * 8]);
  }
  __syncthreads();

  f32x4 acc[4][4];
  #pragma unroll
  for (int i = 0; i < 4; ++i)
    #pragma unroll
    for (int j = 0; j < 4; ++j) acc[i][j] = vzero;

  #pragma unroll
  for (int ks = 0; ks < 2; ++ks) {
    bf16x8 af[4], bfr[4];
    #pragma unroll
    for (int mi = 0; mi < 4; ++mi)
      af[mi] = *reinterpret_cast<const bf16x8*>(
          &As[(wm * 64 + mi * 16 + lo) * LDP + ks * 32 + hi * 8]);
    #pragma unroll
    for (int nj = 0; nj < 4; ++nj)
      bfr[nj] = *reinterpret_cast<const bf16x8*>(
          &Bs[(wn * 64 + nj * 16 + lo) * LDP + ks * 32 + hi * 8]);
    #pragma unroll
    for (int mi = 0; mi < 4; ++mi)
      #pragma unroll
      for (int nj = 0; nj < 4; ++nj)
        acc[mi][nj] = mfma16(af[mi], bfr[nj], acc[mi][nj]);
  }

  #pragma unroll
  for (int nj = 0; nj < 4; ++nj) {
    const int n = n0 + wn * 64 + nj * 16 + lo;
    #pragma unroll
    for (int mi = 0; mi < 4; ++mi) {
      #pragma unroll
      for (int r = 0; r < 4; ++r) {
        const int mm = m0 + wm * 64 + mi * 16 + hi * 4 + r;
        const int bidx = mm >> 11, ss = mm & 2047;
        out[bidx * 2097152L + ss * 1024L + n] = acc[mi][nj][r];
      }
    }
  }
}

// ---------------- fused causal attention (r18: t-split halves, 2x occupancy)
__global__ __launch_bounds__(256) void attn_fused(
    const u16* __restrict__ qh, const u16* __restrict__ kh,
    const u16* __restrict__ vT, u16* __restrict__ outh,
    float* __restrict__ attn_out) {
  __shared__ float pslds[2][4][16][68];  // [strip][wave][row][col]
  __shared__ float lsum[4][2][16];       // [wave][strip][row] l partials
  const int tid = threadIdx.x;
  const int lane = tid & 63, w = tid >> 6;
  const int lo = lane & 15, hi = lane >> 4;
  const int blk = blockIdx.x;
  const int bhz = blk & 31, sb = blk >> 5;  // XCD-grouped: blk%8 == bhz%8; sb 0..31
  const int b = bhz >> 4, h2 = bhz & 15;
  const long bh = (long)bhz * Sc;
  const long rowstride = (long)Hc * Sc;  // 32768
  float* aout = attn_out + (long)b * Sc * rowstride + (long)h2 * Sc;
  float (*pfA)[68] = pslds[0][w];
  float (*pfB)[68] = pslds[1][w];
  const f32x4 vzero = {0.f, 0.f, 0.f, 0.f};
  const int pr = w >> 1, hf = w & 1;   // pair-in-block, t-half
  const int idx = sb * 2 + pr;         // 0..63
  const float M0 = 16.f;

  const int s0A = idx * 16;          // short strip
  const int s0B = (127 - idx) * 16;  // long strip
  const int sendA = (s0A + 79) & ~63;
  const int sendB = (s0B + 79) & ~63;  // sendA < sendB always
  const int srowA = s0A + hi * 4;      // direct-layout row bases
  const int srowB = s0B + hi * 4;
  const int srow2A = s0A + lo;         // z^T rows
  const int srow2B = s0B + lo;
  const f32x4 z4 = {0.f, 0.f, 0.f, 0.f};

  bf16x8 qaA0, qaA1, qaB0, qaB1;
  {
    const u16* qpA = &qh[(bh + s0A + lo) * DHc];
    qaA0 = *reinterpret_cast<const bf16x8*>(&qpA[hi * 8]);
    qaA1 = *reinterpret_cast<const bf16x8*>(&qpA[32 + hi * 8]);
    const u16* qpB = &qh[(bh + s0B + lo) * DHc];
    qaB0 = *reinterpret_cast<const bf16x8*>(&qpB[hi * 8]);
    qaB1 = *reinterpret_cast<const bf16x8*>(&qpB[32 + hi * 8]);
  }

  // ---- pass 1: partial l over this wave's chunks + interleaved zero-fill ----
  float lrA[4], lrB[4];
  #pragma unroll
  for (int r = 0; r < 4; ++r) { lrA[r] = 0.f; lrB[r] = 0.f; }
  int tfA = sendA + hf * 64, tfB = sendB + hf * 64;  // fill cursors, step 128

  for (int t0 = hf * 64; t0 < sendB; t0 += 128) {
    bf16x8 kb[4][2];
    #pragma unroll
    for (int c = 0; c < 4; ++c) {
      const u16* kp = &kh[(bh + t0 + c * 16 + lo) * DHc];
      kb[c][0] = *reinterpret_cast<const bf16x8*>(&kp[hi * 8]);
      kb[c][1] = *reinterpret_cast<const bf16x8*>(&kp[32 + hi * 8]);
    }
    // interleaved zero-fill: one 64-col chunk per iteration
    if (tfA < Sc) {
      #pragma unroll
      for (int r = 0; r < 4; ++r)
        __builtin_nontemporal_store(
            z4, reinterpret_cast<f32x4*>(aout + (long)(srowA + r) * rowstride + tfA + lo * 4));
      tfA += 128;
    } else if (tfB < Sc) {
      #pragma unroll
      for (int r = 0; r < 4; ++r)
        __builtin_nontemporal_store(
            z4, reinterpret_cast<f32x4*>(aout + (long)(srowB + r) * rowstride + tfB + lo * 4));
      tfB += 128;
    }
    const bool doA = (t0 < sendA);  // wave-uniform
    __builtin_amdgcn_s_setprio(1);
    {
      const bool fullB = (t0 + 63 <= s0B);
      #pragma unroll
      for (int c = 0; c < 4; ++c) {
        f32x4 z = mfma16(qaB1, kb[c][1], mfma16(qaB0, kb[c][0], vzero));
        #pragma unroll
        for (int r = 0; r < 4; ++r) {
          float e = exp2f(z[r] - M0);
          if (!fullB) e = ((t0 + c * 16 + lo) <= srowB + r) ? e : 0.f;
          lrB[r] += e;
        }
      }
    }
    if (doA) {
      const bool fullA = (t0 + 63 <= s0A);
      #pragma unroll
      for (int c = 0; c < 4; ++c) {
        f32x4 z = mfma16(qaA1, kb[c][1], mfma16(qaA0, kb[c][0], vzero));
        #pragma unroll
        for (int r = 0; r < 4; ++r) {
          float e = exp2f(z[r] - M0);
          if (!fullA) e = ((t0 + c * 16 + lo) <= srowA + r) ? e : 0.f;
          lrA[r] += e;
        }
      }
    }
    __builtin_amdgcn_s_setprio(0);
  }
  // reduce across the 16 column-lanes; publish partials; merge with partner half
  #pragma unroll
  for (int r = 0; r < 4; ++r) {
    #pragma unroll
    for (int dd = 1; dd < 16; dd <<= 1) {
      lrA[r] += __shfl_xor(lrA[r], dd);
      lrB[r] += __shfl_xor(lrB[r], dd);
    }
  }
  if (lo == 0) {
    #pragma unroll
    for (int r = 0; r < 4; ++r) {
      lsum[w][0][hi * 4 + r] = lrA[r];
      lsum[w][1][hi * 4 + r] = lrB[r];
    }
  }
  __syncthreads();
  const int pw = w ^ 1;  // partner wave (other half of same pair)
  const float offA = M0 + __log2f(lsum[w][0][lo] + lsum[pw][0][lo]);
  const float offB = M0 + __log2f(lsum[w][1][lo] + lsum[pw][1][lo]);

  // ---- pass 2: z^T recompute over own chunks, p-stores + partial PV ----
  f32x4 accoA[4], accoB[4];
  #pragma unroll
  for (int eb = 0; eb < 4; ++eb) { accoA[eb] = vzero; accoB[eb] = vzero; }
  const int r4 = lane >> 4;        // store row-within-quad
  const int c4 = (lane & 15) * 4;  // store col

  for (int t0 = hf * 64; t0 < sendB; t0 += 128) {
    bf16x8 kb[4][2];
    #pragma unroll
    for (int c = 0; c < 4; ++c) {
      const u16* kp = &kh[(bh + t0 + c * 16 + lo) * DHc];
      kb[c][0] = *reinterpret_cast<const bf16x8*>(&kp[hi * 8]);
      kb[c][1] = *reinterpret_cast<const bf16x8*>(&kp[32 + hi * 8]);
    }
    const bool doA = (t0 < sendA);  // wave-uniform
    __builtin_amdgcn_s_setprio(1);
    {
      const bool fullB = (t0 + 63 <= s0B);
      #pragma unroll
      for (int c = 0; c < 4; ++c) {
        f32x4 zt = mfma16(kb[c][1], qaB1, mfma16(kb[c][0], qaB0, vzero));
        f32x4 p;
        #pragma unroll
        for (int r = 0; r < 4; ++r) {
          const float e = exp2f(zt[r] - offB);
          p[r] = (fullB || (t0 + c * 16 + hi * 4 + r <= srow2B)) ? e : 0.f;
        }
        *reinterpret_cast<f32x4*>(&pfB[lo][c * 16 + hi * 4]) = p;
      }
    }
    if (doA) {
      const bool fullA = (t0 + 63 <= s0A);
      #pragma unroll
      for (int c = 0; c < 4; ++c) {
        f32x4 zt = mfma16(kb[c][1], qaA1, mfma16(kb[c][0], qaA0, vzero));
        f32x4 p;
        #pragma unroll
        for (int r = 0; r < 4; ++r) {
          const float e = exp2f(zt[r] - offA);
          p[r] = (fullA || (t0 + c * 16 + hi * 4 + r <= srow2A)) ? e : 0.f;
        }
        *reinterpret_cast<f32x4*>(&pfA[lo][c * 16 + hi * 4]) = p;
      }
    }
    __builtin_amdgcn_s_setprio(0);
    asm volatile("s_waitcnt lgkmcnt(0)" ::: "memory");
    __builtin_amdgcn_sched_barrier(0);
    // transposed nontemporal stores: 4 rows x 256B contiguous per inst
    #pragma unroll
    for (int j = 0; j < 4; ++j) {
      f32x4 v = *reinterpret_cast<const f32x4*>(&pfB[j * 4 + r4][c4]);
      __builtin_nontemporal_store(
          v, reinterpret_cast<f32x4*>(aout + (long)(s0B + j * 4 + r4) * rowstride + t0 + c4));
    }
    if (doA) {
      #pragma unroll
      for (int j = 0; j < 4; ++j) {
        f32x4 v = *reinterpret_cast<const f32x4*>(&pfA[j * 4 + r4][c4]);
        __builtin_nontemporal_store(
            v, reinterpret_cast<f32x4*>(aout + (long)(s0A + j * 4 + r4) * rowstride + t0 + c4));
      }
    }
    // PV: vT fragments loaded once, consumed by both strips
    bf16x8 vb[4][2];
    const u16* vp = &vT[((long)b * DHc + lo) * Sc + t0 + hi * 8];
    #pragma unroll
    for (int eb = 0; eb < 4; ++eb) {
      vb[eb][0] = *reinterpret_cast<const bf16x8*>(&vp[(long)eb * 16 * Sc]);
      vb[eb][1] = *reinterpret_cast<const bf16x8*>(&vp[(long)eb * 16 * Sc + 32]);
    }
    __builtin_amdgcn_s_setprio(1);
    {
      f32x4 a0 = *reinterpret_cast<const f32x4*>(&pfB[lo][hi * 8]);
      f32x4 a1 = *reinterpret_cast<const f32x4*>(&pfB[lo][hi * 8 + 4]);
      f32x4 a2 = *reinterpret_cast<const f32x4*>(&pfB[lo][32 + hi * 8]);
      f32x4 a3 = *reinterpret_cast<const f32x4*>(&pfB[lo][32 + hi * 8 + 4]);
      bf16x8 pa0 = pk8(a0, a1);
      bf16x8 pa1 = pk8(a2, a3);
      #pragma unroll
      for (int eb = 0; eb < 4; ++eb)
        accoB[eb] = mfma16(pa1, vb[eb][1], mfma16(pa0, vb[eb][0], accoB[eb]));
    }
    if (doA) {
      f32x4 a0 = *reinterpret_cast<const f32x4*>(&pfA[lo][hi * 8]);
      f32x4 a1 = *reinterpret_cast<const f32x4*>(&pfA[lo][hi * 8 + 4]);
      f32x4 a2 = *reinterpret_cast<const f32x4*>(&pfA[lo][32 + hi * 8]);
      f32x4 a3 = *reinterpret_cast<const f32x4*>(&pfA[lo][32 + hi * 8 + 4]);
      bf16x8 pa0 = pk8(a0, a1);
      bf16x8 pa1 = pk8(a2, a3);
      #pragma unroll
      for (int eb = 0; eb < 4; ++eb)
        accoA[eb] = mfma16(pa1, vb[eb][1], mfma16(pa0, vb[eb][0], accoA[eb]));
    }
    __builtin_amdgcn_s_setprio(0);
  }

  // ---- merge partial PV across halves (reuse pf buffers) + outh store ----
  #pragma unroll
  for (int eb = 0; eb < 4; ++eb)
    #pragma unroll
    for (int r = 0; r < 4; ++r) {
      pfA[hi * 4 + r][eb * 16 + lo] = accoA[eb][r];
      pfB[hi * 4 + r][eb * 16 + lo] = accoB[eb][r];
    }
  __syncthreads();
  {
    // wave half hf merges strip index hf of its pair (h=0 -> A, h=1 -> B)
    const int w0 = w & ~1;
    const int s0S = hf ? s0B : s0A;
    #pragma unroll
    for (int rr = 0; rr < 4; ++rr) {
      const int row = rr * 4 + (lane >> 4);
      const int col = (lane & 15) * 4;
      f32x4 x = *reinterpret_cast<const f32x4*>(&pslds[hf][w0][row][col]);
      f32x4 y = *reinterpret_cast<const f32x4*>(&pslds[hf][w0 + 1][row][col]);
      ushort4 o;
      o.x = f2bf(x[0] + y[0]); o.y = f2bf(x[1] + y[1]);
      o.z = f2bf(x[2] + y[2]); o.w = f2bf(x[3] + y[3]);
      *reinterpret_cast<ushort4*>(&outh[(bh + s0S + row) * DHc + col]) = o;
    }
  }

  // ---- drain any remaining zero-fill ----
  for (int t0 = tfA; t0 < Sc; t0 += 128) {
    #pragma unroll
    for (int r = 0; r < 4; ++r)
      __builtin_nontemporal_store(
          z4, reinterpret_cast<f32x4*>(aout + (long)(srowA + r) * rowstride + t0 + lo * 4));
  }
  for (int t0 = tfB; t0 < Sc; t0 += 128) {
    #pragma unroll
    for (int r = 0; r < 4; ++r)
      __builtin_nontemporal_store(
          z4, reinterpret_cast<f32x4*>(aout + (long)(srowB + r) * rowstride + t0 + lo * 4));
  }
}

extern "C" void kernel_launch(void* const* d_in, const int* in_sizes, int n_in,
                              void* d_out, int out_size, void* d_ws, size_t ws_size,
                              hipStream_t stream) {
  (void)in_sizes; (void)n_in; (void)out_size; (void)ws_size;
  const float* q  = (const float*)d_in[0];
  const float* k  = (const float*)d_in[1];
  const float* v  = (const float*)d_in[2];
  const float* Wv = (const float*)d_in[4];
  const float* bv = (const float*)d_in[5];
  const float* Wq = (const float*)d_in[6];
  const float* bq = (const float*)d_in[7];
  const float* Wk = (const float*)d_in[8];
  const float* bk = (const float*)d_in[9];
  const float* Wo = (const float*)d_in[10];

  char* ws = (char*)d_ws;
  u16* qbf   = (u16*)(ws + 0);          // 8.0 MB
  u16* kbf   = (u16*)(ws + 8388608);
  u16* vbf   = (u16*)(ws + 16777216);
  u16* Wqbf  = (u16*)(ws + 25165824);   // 2 MB
  u16* Wkbf  = (u16*)(ws + 27262976);
  u16* Wvbf  = (u16*)(ws + 29360128);   // 128 KB
  u16* Wobf  = (u16*)(ws + 29491200);
  u16* qhb   = (u16*)(ws + 29622272);   // 8 MB  [B,H,S,DH]
  u16* khb   = (u16*)(ws + 38010880);
  u16* vTb   = (u16*)(ws + 46399488);   // 512 KB [B,DH,S]
  u16* outh  = (u16*)(ws + 46923776);   // 8 MB  [B,H,S,DH]

  float* outp  = (float*)d_out;
  float* attnp = (float*)d_out + (long)Bc * Sc * Dc;

  // one launch: all f32 -> bf16 conversions (3.7M float4)
  cvt_all<<<(3702784 + 255) / 256, 256, 0, stream>>>(
      q, k, v, Wq, Wk, Wv, Wo, qbf, kbf, vbf, Wqbf, Wkbf, Wvbf, Wobf);

  // qh scale folds 1/sqrt(DH) AND log2(e): attention runs in exp2 domain
  const float qscale = 0.125f * 1.4426950408889634f;
  gemm_qkv<<<dim3(32, 16, 3), 256, 0, stream>>>(
      qbf, kbf, vbf, Wqbf, Wkbf, Wvbf, bq, bk, bv, qscale, qhb, khb, vTb);

  attn_fused<<<1024, 256, 0, stream>>>(qhb, khb, vTb, outh, attnp);

  // fused mean-over-heads + final projection
  gemm_final<<<dim3(32, 8), 256, 0, stream>>>(outh, Wobf, outp);
}

// Round 22
// 217.410 us; speedup vs baseline: 1.0458x; 1.0458x over previous
//
#include <hip/hip_runtime.h>
#include <cstdint>
#include <math.h>

typedef unsigned short u16;
typedef __bf16 bf16x8 __attribute__((ext_vector_type(8)));
typedef float f32x4 __attribute__((ext_vector_type(4)));

constexpr int Bc = 2, Sc = 2048, Dc = 1024, Hc = 16, DHc = 64;

__device__ __forceinline__ u16 f2bf(float f) {
  uint32_t u = __builtin_bit_cast(uint32_t, f);
  u += 0x7fffu + ((u >> 16) & 1u);
  return (u16)(u >> 16);
}
__device__ __forceinline__ float bf2f(u16 h) {
  uint32_t u = ((uint32_t)h) << 16;
  return __builtin_bit_cast(float, u);
}
__device__ __forceinline__ f32x4 mfma16(bf16x8 a, bf16x8 b, f32x4 c) {
  return __builtin_amdgcn_mfma_f32_16x16x32_bf16(a, b, c, 0, 0, 0);
}
// async global->LDS, 16B per lane; LDS base must be wave-uniform, global addr per-lane
__device__ __forceinline__ void gload16(const void* g, void* l) {
  __builtin_amdgcn_global_load_lds((const uint32_t*)g, (uint32_t*)l, 16, 0, 0);
}
// two f32x4 -> bf16x8 (RNE)
__device__ __forceinline__ bf16x8 pk8(f32x4 a, f32x4 b) {
  alignas(16) u16 t[8];
  #pragma unroll
  for (int j = 0; j < 4; ++j) { t[j] = f2bf(a[j]); t[4 + j] = f2bf(b[j]); }
  return *reinterpret_cast<const bf16x8*>(t);
}

// ---------------- single-launch f32 -> bf16 conversion of all 7 tensors ----------------
__global__ __launch_bounds__(256) void cvt_all(
    const float* __restrict__ q, const float* __restrict__ k, const float* __restrict__ v,
    const float* __restrict__ Wq, const float* __restrict__ Wk,
    const float* __restrict__ Wv, const float* __restrict__ Wo,
    u16* __restrict__ qo, u16* __restrict__ ko, u16* __restrict__ vo,
    u16* __restrict__ Wqo, u16* __restrict__ Wko, u16* __restrict__ Wvo,
    u16* __restrict__ Woo) {
  constexpr int NQ = Bc * Sc * Dc / 4;      // 1048576 float4 per q/k/v
  constexpr int NW = Hc * DHc * Dc / 4;     // 262144 per Wq/Wk
  constexpr int NS = DHc * Dc / 4;          // 16384 per Wv/Wo
  constexpr int C1 = NQ, C2 = 2 * NQ, C3 = 3 * NQ;
  constexpr int C4 = C3 + NW, C5 = C4 + NW, C6 = C5 + NS, C7 = C6 + NS;
  const int i = blockIdx.x * 256 + threadIdx.x;
  if (i >= C7) return;
  const float* src; u16* dst; int j;
  if (i < C1)      { src = q;  dst = qo;  j = i; }
  else if (i < C2) { src = k;  dst = ko;  j = i - C1; }
  else if (i < C3) { src = v;  dst = vo;  j = i - C2; }
  else if (i < C4) { src = Wq; dst = Wqo; j = i - C3; }
  else if (i < C5) { src = Wk; dst = Wko; j = i - C4; }
  else if (i < C6) { src = Wv; dst = Wvo; j = i - C5; }
  else             { src = Wo; dst = Woo; j = i - C6; }
  float4 x = reinterpret_cast<const float4*>(src)[j];
  ushort4 o;
  o.x = f2bf(x.x); o.y = f2bf(x.y); o.z = f2bf(x.z); o.w = f2bf(x.w);
  reinterpret_cast<ushort4*>(dst)[j] = o;
}

// ---------------- combined q+k+v projection GEMM; z selects operand set.
// Grid (32, 8, 3): blockIdx.x = m-tile, blockIdx.y = n-tile (XCD-grouped by m).
__global__ __launch_bounds__(256) void gemm_qkv(
    const u16* __restrict__ qbf, const u16* __restrict__ kbf, const u16* __restrict__ vbf,
    const u16* __restrict__ Wqb, const u16* __restrict__ Wkb, const u16* __restrict__ Wvb,
    const float* __restrict__ bq, const float* __restrict__ bk, const float* __restrict__ bv,
    float qscale, u16* __restrict__ qh, u16* __restrict__ kh, u16* __restrict__ vT) {
  constexpr int K = 1024;
  const int z = blockIdx.z;
  if (z == 2 && blockIdx.y != 0) return;
  const u16* A  = z == 0 ? qbf : (z == 1 ? kbf : vbf);
  const u16* Bw = z == 0 ? Wqb : (z == 1 ? Wkb : Wvb);
  const float* bias = z == 0 ? bq : (z == 1 ? bk : bv);
  const float scale = z == 0 ? qscale : 1.0f;

  __shared__ u16 As[128 * 32];
  __shared__ u16 Bs[128 * 32];
  const int tid = threadIdx.x;
  const int lane = tid & 63;
  const int w = tid >> 6, wm = w >> 1, wn = w & 1;
  const int lo = lane & 15, hi = lane >> 4;
  const int m0 = blockIdx.x * 128, n0 = blockIdx.y * 128;
  const int r16 = lane >> 2;
  const int c8 = (lane & 3) * 8;
  const f32x4 vzero = {0.f, 0.f, 0.f, 0.f};

  f32x4 acc[4][4];
  #pragma unroll
  for (int i = 0; i < 4; ++i)
    #pragma unroll
    for (int j = 0; j < 4; ++j) acc[i][j] = vzero;

  for (int k0 = 0; k0 < K; k0 += 32) {
    #pragma unroll
    for (int it = 0; it < 2; ++it) {
      const int rg = w * 2 + it;
      const int row = rg * 16 + r16;
      gload16(&A[(long)(m0 + row) * K + k0 + c8], &As[rg * 512]);
      gload16(&Bw[(long)(n0 + row) * K + k0 + c8], &Bs[rg * 512]);
    }
    __syncthreads();
    bf16x8 af[4], bfr[4];
    #pragma unroll
    for (int mi = 0; mi < 4; ++mi)
      af[mi] = *reinterpret_cast<const bf16x8*>(&As[(wm * 64 + mi * 16 + lo) * 32 + hi * 8]);
    #pragma unroll
    for (int nj = 0; nj < 4; ++nj)
      bfr[nj] = *reinterpret_cast<const bf16x8*>(&Bs[(wn * 64 + nj * 16 + lo) * 32 + hi * 8]);
    #pragma unroll
    for (int mi = 0; mi < 4; ++mi)
      #pragma unroll
      for (int nj = 0; nj < 4; ++nj)
        acc[mi][nj] = mfma16(af[mi], bfr[nj], acc[mi][nj]);
    __syncthreads();
  }

  #pragma unroll
  for (int nj = 0; nj < 4; ++nj) {
    const int n = n0 + wn * 64 + nj * 16 + lo;
    if (z == 2 && n >= 64) continue;
    const float bb = bias[n];
    #pragma unroll
    for (int mi = 0; mi < 4; ++mi) {
      #pragma unroll
      for (int r = 0; r < 4; ++r) {
        const int mm = m0 + wm * 64 + mi * 16 + hi * 4 + r;
        const int bidx = mm >> 11, ss = mm & 2047;
        const float val = (acc[mi][nj][r] + bb) * scale;
        if (z < 2) {
          const int hh = n >> 6, ee = n & 63;
          const long idx = bidx * 2097152L + ss * 64L + hh * 131072L + ee;
          (z ? kh : qh)[idx] = f2bf(val);
        } else {
          vT[bidx * 131072L + n * 2048L + ss] = f2bf(val);
        }
      }
    }
  }
}

// ---------------- fused mean-over-heads + final projection GEMM
// out[b,s,n] = sum_e (mean_h outh[b,h,s,e]) * Wo[n][e]
// Grid (32, 8): x = m-tile (XCD-grouped A re-stage), y = n-tile. K=64 whole.
__global__ __launch_bounds__(256) void gemm_final(
    const u16* __restrict__ outh, const u16* __restrict__ Wob,
    float* __restrict__ out) {
  constexpr int LDP = 72;  // 64 + 8 pad -> <=2-way ds_read_b128 conflicts
  __shared__ u16 As[128 * LDP];
  __shared__ u16 Bs[128 * LDP];
  const int tid = threadIdx.x;
  const int lane = tid & 63;
  const int w = tid >> 6, wm = w >> 1, wn = w & 1;
  const int lo = lane & 15, hi = lane >> 4;
  const int m0 = blockIdx.x * 128, n0 = blockIdx.y * 128;
  const f32x4 vzero = {0.f, 0.f, 0.f, 0.f};

  // stage A = mean over 16 heads (reg-accumulate, coalesced 128B rows)
  {
    const int row = tid >> 1;         // 0..127
    const int c0 = (tid & 1) * 32;    // 0 / 32
    const int mm = m0 + row;
    const int b = mm >> 11, ss = mm & 2047;
    float acc[32];
    #pragma unroll
    for (int j = 0; j < 32; ++j) acc[j] = 0.f;
    for (int h = 0; h < Hc; ++h) {
      const u16* p = &outh[((long)(b * Hc + h) * Sc + ss) * DHc + c0];
      #pragma unroll
      for (int g = 0; g < 4; ++g) {
        alignas(16) u16 t[8];
        *reinterpret_cast<uint4*>(t) = *reinterpret_cast<const uint4*>(&p[g * 8]);
        #pragma unroll
        for (int j = 0; j < 8; ++j) acc[g * 8 + j] += bf2f(t[j]);
      }
    }
    #pragma unroll
    for (int g = 0; g < 4; ++g) {
      alignas(16) u16 t[8];
      #pragma unroll
      for (int j = 0; j < 8; ++j) t[j] = f2bf(acc[g * 8 + j] * 0.0625f);
      *reinterpret_cast<uint4*>(&As[row * LDP + c0 + g * 8]) =
          *reinterpret_cast<const uint4*>(t);
    }
    // stage B = Wo rows n0..n0+127
    const u16* pb = &Wob[(long)(n0 + row) * DHc + c0];
    #pragma unroll
    for (int g = 0; g < 4; ++g)
      *reinterpret_cast<uint4*>(&Bs[row * LDP + c0 + g * 8]) =
          *reinterpret_cast<const uint4*>(&pb[g * 8]);
  }
  __syncthreads();

  f32x4 acc[4][4];
  #pragma unroll
  for (int i = 0; i < 4; ++i)
    #pragma unroll
    for (int j = 0; j < 4; ++j) acc[i][j] = vzero;

  #pragma unroll
  for (int ks = 0; ks < 2; ++ks) {
    bf16x8 af[4], bfr[4];
    #pragma unroll
    for (int mi = 0; mi < 4; ++mi)
      af[mi] = *reinterpret_cast<const bf16x8*>(
          &As[(wm * 64 + mi * 16 + lo) * LDP + ks * 32 + hi * 8]);
    #pragma unroll
    for (int nj = 0; nj < 4; ++nj)
      bfr[nj] = *reinterpret_cast<const bf16x8*>(
          &Bs[(wn * 64 + nj * 16 + lo) * LDP + ks * 32 + hi * 8]);
    #pragma unroll
    for (int mi = 0; mi < 4; ++mi)
      #pragma unroll
      for (int nj = 0; nj < 4; ++nj)
        acc[mi][nj] = mfma16(af[mi], bfr[nj], acc[mi][nj]);
  }

  #pragma unroll
  for (int nj = 0; nj < 4; ++nj) {
    const int n = n0 + wn * 64 + nj * 16 + lo;
    #pragma unroll
    for (int mi = 0; mi < 4; ++mi) {
      #pragma unroll
      for (int r = 0; r < 4; ++r) {
        const int mm = m0 + wm * 64 + mi * 16 + hi * 4 + r;
        const int bidx = mm >> 11, ss = mm & 2047;
        out[bidx * 2097152L + ss * 1024L + n] = acc[mi][nj][r];
      }
    }
  }
}

// ---------------- fused causal attention (r18: t-split halves, 2x occupancy)
__global__ __launch_bounds__(256) void attn_fused(
    const u16* __restrict__ qh, const u16* __restrict__ kh,
    const u16* __restrict__ vT, u16* __restrict__ outh,
    float* __restrict__ attn_out) {
  __shared__ float pslds[2][4][16][68];  // [strip][wave][row][col]
  __shared__ float lsum[4][2][16];       // [wave][strip][row] l partials
  const int tid = threadIdx.x;
  const int lane = tid & 63, w = tid >> 6;
  const int lo = lane & 15, hi = lane >> 4;
  const int blk = blockIdx.x;
  const int bhz = blk & 31, sb = blk >> 5;  // XCD-grouped: blk%8 == bhz%8; sb 0..31
  const int b = bhz >> 4, h2 = bhz & 15;
  const long bh = (long)bhz * Sc;
  const long rowstride = (long)Hc * Sc;  // 32768
  float* aout = attn_out + (long)b * Sc * rowstride + (long)h2 * Sc;
  float (*pfA)[68] = pslds[0][w];
  float (*pfB)[68] = pslds[1][w];
  const f32x4 vzero = {0.f, 0.f, 0.f, 0.f};
  const int pr = w >> 1, hf = w & 1;   // pair-in-block, t-half
  const int idx = sb * 2 + pr;         // 0..63
  const float M0 = 16.f;

  const int s0A = idx * 16;          // short strip
  const int s0B = (127 - idx) * 16;  // long strip
  const int sendA = (s0A + 79) & ~63;
  const int sendB = (s0B + 79) & ~63;  // sendA < sendB always
  const int srowA = s0A + hi * 4;      // direct-layout row bases
  const int srowB = s0B + hi * 4;
  const int srow2A = s0A + lo;         // z^T rows
  const int srow2B = s0B + lo;
  const f32x4 z4 = {0.f, 0.f, 0.f, 0.f};

  bf16x8 qaA0, qaA1, qaB0, qaB1;
  {
    const u16* qpA = &qh[(bh + s0A + lo) * DHc];
    qaA0 = *reinterpret_cast<const bf16x8*>(&qpA[hi * 8]);
    qaA1 = *reinterpret_cast<const bf16x8*>(&qpA[32 + hi * 8]);
    const u16* qpB = &qh[(bh + s0B + lo) * DHc];
    qaB0 = *reinterpret_cast<const bf16x8*>(&qpB[hi * 8]);
    qaB1 = *reinterpret_cast<const bf16x8*>(&qpB[32 + hi * 8]);
  }

  // ---- pass 1: partial l over this wave's chunks + interleaved zero-fill ----
  float lrA[4], lrB[4];
  #pragma unroll
  for (int r = 0; r < 4; ++r) { lrA[r] = 0.f; lrB[r] = 0.f; }
  int tfA = sendA + hf * 64, tfB = sendB + hf * 64;  // fill cursors, step 128

  for (int t0 = hf * 64; t0 < sendB; t0 += 128) {
    bf16x8 kb[4][2];
    #pragma unroll
    for (int c = 0; c < 4; ++c) {
      const u16* kp = &kh[(bh + t0 + c * 16 + lo) * DHc];
      kb[c][0] = *reinterpret_cast<const bf16x8*>(&kp[hi * 8]);
      kb[c][1] = *reinterpret_cast<const bf16x8*>(&kp[32 + hi * 8]);
    }
    // interleaved zero-fill: one 64-col chunk per iteration
    if (tfA < Sc) {
      #pragma unroll
      for (int r = 0; r < 4; ++r)
        __builtin_nontemporal_store(
            z4, reinterpret_cast<f32x4*>(aout + (long)(srowA + r) * rowstride + tfA + lo * 4));
      tfA += 128;
    } else if (tfB < Sc) {
      #pragma unroll
      for (int r = 0; r < 4; ++r)
        __builtin_nontemporal_store(
            z4, reinterpret_cast<f32x4*>(aout + (long)(srowB + r) * rowstride + tfB + lo * 4));
      tfB += 128;
    }
    const bool doA = (t0 < sendA);  // wave-uniform
    __builtin_amdgcn_s_setprio(1);
    {
      const bool fullB = (t0 + 63 <= s0B);
      #pragma unroll
      for (int c = 0; c < 4; ++c) {
        f32x4 z = mfma16(qaB1, kb[c][1], mfma16(qaB0, kb[c][0], vzero));
        #pragma unroll
        for (int r = 0; r < 4; ++r) {
          float e = exp2f(z[r] - M0);
          if (!fullB) e = ((t0 + c * 16 + lo) <= srowB + r) ? e : 0.f;
          lrB[r] += e;
        }
      }
    }
    if (doA) {
      const bool fullA = (t0 + 63 <= s0A);
      #pragma unroll
      for (int c = 0; c < 4; ++c) {
        f32x4 z = mfma16(qaA1, kb[c][1], mfma16(qaA0, kb[c][0], vzero));
        #pragma unroll
        for (int r = 0; r < 4; ++r) {
          float e = exp2f(z[r] - M0);
          if (!fullA) e = ((t0 + c * 16 + lo) <= srowA + r) ? e : 0.f;
          lrA[r] += e;
        }
      }
    }
    __builtin_amdgcn_s_setprio(0);
  }
  // reduce across the 16 column-lanes; publish partials; merge with partner half
  #pragma unroll
  for (int r = 0; r < 4; ++r) {
    #pragma unroll
    for (int dd = 1; dd < 16; dd <<= 1) {
      lrA[r] += __shfl_xor(lrA[r], dd);
      lrB[r] += __shfl_xor(lrB[r], dd);
    }
  }
  if (lo == 0) {
    #pragma unroll
    for (int r = 0; r < 4; ++r) {
      lsum[w][0][hi * 4 + r] = lrA[r];
      lsum[w][1][hi * 4 + r] = lrB[r];
    }
  }
  __syncthreads();
  const int pw = w ^ 1;  // partner wave (other half of same pair)
  const float offA = M0 + __log2f(lsum[w][0][lo] + lsum[pw][0][lo]);
  const float offB = M0 + __log2f(lsum[w][1][lo] + lsum[pw][1][lo]);

  // ---- pass 2: z^T recompute over own chunks, p-stores + partial PV ----
  f32x4 accoA[4], accoB[4];
  #pragma unroll
  for (int eb = 0; eb < 4; ++eb) { accoA[eb] = vzero; accoB[eb] = vzero; }
  const int r4 = lane >> 4;        // store row-within-quad
  const int c4 = (lane & 15) * 4;  // store col

  for (int t0 = hf * 64; t0 < sendB; t0 += 128) {
    bf16x8 kb[4][2];
    #pragma unroll
    for (int c = 0; c < 4; ++c) {
      const u16* kp = &kh[(bh + t0 + c * 16 + lo) * DHc];
      kb[c][0] = *reinterpret_cast<const bf16x8*>(&kp[hi * 8]);
      kb[c][1] = *reinterpret_cast<const bf16x8*>(&kp[32 + hi * 8]);
    }
    const bool doA = (t0 < sendA);  // wave-uniform
    __builtin_amdgcn_s_setprio(1);
    {
      const bool fullB = (t0 + 63 <= s0B);
      #pragma unroll
      for (int c = 0; c < 4; ++c) {
        f32x4 zt = mfma16(kb[c][1], qaB1, mfma16(kb[c][0], qaB0, vzero));
        f32x4 p;
        #pragma unroll
        for (int r = 0; r < 4; ++r) {
          const float e = exp2f(zt[r] - offB);
          p[r] = (fullB || (t0 + c * 16 + hi * 4 + r <= srow2B)) ? e : 0.f;
        }
        *reinterpret_cast<f32x4*>(&pfB[lo][c * 16 + hi * 4]) = p;
      }
    }
    if (doA) {
      const bool fullA = (t0 + 63 <= s0A);
      #pragma unroll
      for (int c = 0; c < 4; ++c) {
        f32x4 zt = mfma16(kb[c][1], qaA1, mfma16(kb[c][0], qaA0, vzero));
        f32x4 p;
        #pragma unroll
        for (int r = 0; r < 4; ++r) {
          const float e = exp2f(zt[r] - offA);
          p[r] = (fullA || (t0 + c * 16 + hi * 4 + r <= srow2A)) ? e : 0.f;
        }
        *reinterpret_cast<f32x4*>(&pfA[lo][c * 16 + hi * 4]) = p;
      }
    }
    __builtin_amdgcn_s_setprio(0);
    asm volatile("s_waitcnt lgkmcnt(0)" ::: "memory");
    __builtin_amdgcn_sched_barrier(0);
    // transposed nontemporal stores: 4 rows x 256B contiguous per inst
    #pragma unroll
    for (int j = 0; j < 4; ++j) {
      f32x4 v = *reinterpret_cast<const f32x4*>(&pfB[j * 4 + r4][c4]);
      __builtin_nontemporal_store(
          v, reinterpret_cast<f32x4*>(aout + (long)(s0B + j * 4 + r4) * rowstride + t0 + c4));
    }
    if (doA) {
      #pragma unroll
      for (int j = 0; j < 4; ++j) {
        f32x4 v = *reinterpret_cast<const f32x4*>(&pfA[j * 4 + r4][c4]);
        __builtin_nontemporal_store(
            v, reinterpret_cast<f32x4*>(aout + (long)(s0A + j * 4 + r4) * rowstride + t0 + c4));
      }
    }
    // PV: vT fragments loaded once, consumed by both strips
    bf16x8 vb[4][2];
    const u16* vp = &vT[((long)b * DHc + lo) * Sc + t0 + hi * 8];
    #pragma unroll
    for (int eb = 0; eb < 4; ++eb) {
      vb[eb][0] = *reinterpret_cast<const bf16x8*>(&vp[(long)eb * 16 * Sc]);
      vb[eb][1] = *reinterpret_cast<const bf16x8*>(&vp[(long)eb * 16 * Sc + 32]);
    }
    __builtin_amdgcn_s_setprio(1);
    {
      f32x4 a0 = *reinterpret_cast<const f32x4*>(&pfB[lo][hi * 8]);
      f32x4 a1 = *reinterpret_cast<const f32x4*>(&pfB[lo][hi * 8 + 4]);
      f32x4 a2 = *reinterpret_cast<const f32x4*>(&pfB[lo][32 + hi * 8]);
      f32x4 a3 = *reinterpret_cast<const f32x4*>(&pfB[lo][32 + hi * 8 + 4]);
      bf16x8 pa0 = pk8(a0, a1);
      bf16x8 pa1 = pk8(a2, a3);
      #pragma unroll
      for (int eb = 0; eb < 4; ++eb)
        accoB[eb] = mfma16(pa1, vb[eb][1], mfma16(pa0, vb[eb][0], accoB[eb]));
    }
    if (doA) {
      f32x4 a0 = *reinterpret_cast<const f32x4*>(&pfA[lo][hi * 8]);
      f32x4 a1 = *reinterpret_cast<const f32x4*>(&pfA[lo][hi * 8 + 4]);
      f32x4 a2 = *reinterpret_cast<const f32x4*>(&pfA[lo][32 + hi * 8]);
      f32x4 a3 = *reinterpret_cast<const f32x4*>(&pfA[lo][32 + hi * 8 + 4]);
      bf16x8 pa0 = pk8(a0, a1);
      bf16x8 pa1 = pk8(a2, a3);
      #pragma unroll
      for (int eb = 0; eb < 4; ++eb)
        accoA[eb] = mfma16(pa1, vb[eb][1], mfma16(pa0, vb[eb][0], accoA[eb]));
    }
    __builtin_amdgcn_s_setprio(0);
  }

  // ---- merge partial PV across halves (reuse pf buffers) + outh store ----
  #pragma unroll
  for (int eb = 0; eb < 4; ++eb)
    #pragma unroll
    for (int r = 0; r < 4; ++r) {
      pfA[hi * 4 + r][eb * 16 + lo] = accoA[eb][r];
      pfB[hi * 4 + r][eb * 16 + lo] = accoB[eb][r];
    }
  __syncthreads();
  {
    // wave half hf merges strip index hf of its pair (h=0 -> A, h=1 -> B)
    const int w0 = w & ~1;
    const int s0S = hf ? s0B : s0A;
    #pragma unroll
    for (int rr = 0; rr < 4; ++rr) {
      const int row = rr * 4 + (lane >> 4);
      const int col = (lane & 15) * 4;
      f32x4 x = *reinterpret_cast<const f32x4*>(&pslds[hf][w0][row][col]);
      f32x4 y = *reinterpret_cast<const f32x4*>(&pslds[hf][w0 + 1][row][col]);
      ushort4 o;
      o.x = f2bf(x[0] + y[0]); o.y = f2bf(x[1] + y[1]);
      o.z = f2bf(x[2] + y[2]); o.w = f2bf(x[3] + y[3]);
      *reinterpret_cast<ushort4*>(&outh[(bh + s0S + row) * DHc + col]) = o;
    }
  }

  // ---- drain any remaining zero-fill ----
  for (int t0 = tfA; t0 < Sc; t0 += 128) {
    #pragma unroll
    for (int r = 0; r < 4; ++r)
      __builtin_nontemporal_store(
          z4, reinterpret_cast<f32x4*>(aout + (long)(srowA + r) * rowstride + t0 + lo * 4));
  }
  for (int t0 = tfB; t0 < Sc; t0 += 128) {
    #pragma unroll
    for (int r = 0; r < 4; ++r)
      __builtin_nontemporal_store(
          z4, reinterpret_cast<f32x4*>(aout + (long)(srowB + r) * rowstride + t0 + lo * 4));
  }
}

extern "C" void kernel_launch(void* const* d_in, const int* in_sizes, int n_in,
                              void* d_out, int out_size, void* d_ws, size_t ws_size,
                              hipStream_t stream) {
  (void)in_sizes; (void)n_in; (void)out_size; (void)ws_size;
  const float* q  = (const float*)d_in[0];
  const float* k  = (const float*)d_in[1];
  const float* v  = (const float*)d_in[2];
  const float* Wv = (const float*)d_in[4];
  const float* bv = (const float*)d_in[5];
  const float* Wq = (const float*)d_in[6];
  const float* bq = (const float*)d_in[7];
  const float* Wk = (const float*)d_in[8];
  const float* bk = (const float*)d_in[9];
  const float* Wo = (const float*)d_in[10];

  char* ws = (char*)d_ws;
  u16* qbf   = (u16*)(ws + 0);          // 8.0 MB
  u16* kbf   = (u16*)(ws + 8388608);
  u16* vbf   = (u16*)(ws + 16777216);
  u16* Wqbf  = (u16*)(ws + 25165824);   // 2 MB
  u16* Wkbf  = (u16*)(ws + 27262976);
  u16* Wvbf  = (u16*)(ws + 29360128);   // 128 KB (B staging may read into Wobf: defined)
  u16* Wobf  = (u16*)(ws + 29491200);
  u16* qhb   = (u16*)(ws + 29622272);   // 8 MB  [B,H,S,DH]
  u16* khb   = (u16*)(ws + 38010880);
  u16* vTb   = (u16*)(ws + 46399488);   // 512 KB [B,DH,S]
  u16* outh  = (u16*)(ws + 46923776);   // 8 MB  [B,H,S,DH]

  float* outp  = (float*)d_out;
  float* attnp = (float*)d_out + (long)Bc * Sc * Dc;

  // one launch: all f32 -> bf16 conversions (3.7M float4)
  cvt_all<<<(3702784 + 255) / 256, 256, 0, stream>>>(
      q, k, v, Wq, Wk, Wv, Wo, qbf, kbf, vbf, Wqbf, Wkbf, Wvbf, Wobf);

  // qh scale folds 1/sqrt(DH) AND log2(e): attention runs in exp2 domain
  const float qscale = 0.125f * 1.4426950408889634f;
  gemm_qkv<<<dim3(32, 8, 3), 256, 0, stream>>>(
      qbf, kbf, vbf, Wqbf, Wkbf, Wvbf, bq, bk, bv, qscale, qhb, khb, vTb);

  attn_fused<<<1024, 256, 0, stream>>>(qhb, khb, vTb, outh, attnp);

  // fused mean-over-heads + final projection
  gemm_final<<<dim3(32, 8), 256, 0, stream>>>(outh, Wobf, outp);
}